// Round 12
// baseline (326.337 us; speedup 1.0000x reference)
//
#include <hip/hip_runtime.h>
#include <math.h>

// x: [8,512,32,32] fp32 | W_qkv: [1536,512,3,3] fp32 | W_out: [512,512,1,1]
// gamma/beta: [512] | out: [8,512,32,32] fp32
// G=8 heads, D=64 head dim, N=1024 seq (h*w), B=8

#define SMOOTH 1e-4f
#define BN_EPS 1e-5f

typedef __attribute__((ext_vector_type(8))) short bf16x8;
typedef __attribute__((ext_vector_type(8))) unsigned short u16x8;
typedef __attribute__((ext_vector_type(4))) float f32x4;
typedef __attribute__((ext_vector_type(16))) float f32x16;
typedef __attribute__((ext_vector_type(4))) unsigned int u32x4;
typedef __attribute__((ext_vector_type(4))) unsigned short u16x4;

__device__ inline unsigned short bf16rne(float f) {
  unsigned int u = __float_as_uint(f);
  u += 0x7fff + ((u >> 16) & 1);
  return (unsigned short)(u >> 16);
}
__device__ inline float b2f(unsigned short u) {
  return __uint_as_float((unsigned int)u << 16);
}

// Async 16B global->LDS DMA (gfx950). LDS dest = wave-uniform base + lane*16.
// RULE (R8): lane gptr MUST be base + lane*16 (contiguous 1KB/wave).
typedef __attribute__((address_space(1))) void gvoid;
typedef __attribute__((address_space(3))) void lvoid;
__device__ __forceinline__ void async16(const void* g, void* l) {
  __builtin_amdgcn_global_load_lds((gvoid*)g, (lvoid*)l, 16, 0, 0);
}

// ---------------------------------------------------------------------------
// prep_kernel: merged repacks (unchanged from R11).
// ---------------------------------------------------------------------------
__global__ void prep_kernel(const float* __restrict__ wq,
                            unsigned short* __restrict__ wqr2,
                            const float* __restrict__ x,
                            unsigned short* __restrict__ xrp2,
                            const float* __restrict__ wo,
                            unsigned short* __restrict__ wor,
                            float* __restrict__ sums,
                            float* __restrict__ sumsq) {
  __shared__ float Sh[64 * 132];
  const int tid = threadIdx.x;
  const int bid = blockIdx.x;
  if (bid < 3072) {
    const size_t pair0 = (size_t)bid * 256;
    for (int off = tid; off < 576; off += 256)
      *(float4*)(Sh + off * 4) = *(const float4*)(wq + pair0 * 9 + off * 4);
    __syncthreads();
    const int co = (int)(pair0 >> 9);
    const int ciBase = (int)(pair0 & 511);
    const int cotile = co >> 6, co_l = co & 63;
    for (int idx = tid; idx < 288; idx += 256) {
      int t = idx >> 5;
      int oct = idx & 31;
      int ci = ciBase + oct * 8;
      int ci0c = ci >> 5, c4 = oct & 3;
      u16x8 pk;
#pragma unroll
      for (int e = 0; e < 8; ++e) pk[e] = bf16rne(Sh[(oct * 8 + e) * 9 + t]);
      size_t o = (size_t)(ci0c * 24 + cotile) * 18432 +
                 (size_t)((c4 * 9 + t) * 64 + co_l) * 8;
      *(u16x8*)(wqr2 + o) = pk;
    }
  } else if (bid < 3584) {
    const int bx = bid - 3072;
    const int p0 = (bx & 7) * 128;
    const int ci0 = ((bx >> 3) & 7) * 64;
    const int b = bx >> 6;
    for (int k = 0; k < 8; ++k) {
      int idx = tid + k * 256;
      int c4 = idx & 31, row = idx >> 5;
      *(float4*)(Sh + row * 132 + c4 * 4) =
          *(const float4*)(x + ((size_t)(b * 512 + ci0 + row)) * 1024 + p0 + c4 * 4);
    }
    __syncthreads();
    const int pl = tid >> 1, half = tid & 1;
    const int p = p0 + pl;
    const int h = p >> 5, w = p & 31;
#pragma unroll
    for (int v = 0; v < 8; ++v) {
      u16x4 pk;
#pragma unroll
      for (int e = 0; e < 4; ++e)
        pk[e] = bf16rne(Sh[(half * 32 + v * 4 + e) * 132 + pl]);
      int cc = ci0 + half * 32 + v * 4;
      int ci0c = cc >> 5, c4 = (cc >> 3) & 3, e0 = cc & 7;
      size_t gran =
          (size_t)((ci0c * 4 + c4) * 8 + b) * 1156 + (h + 1) * 34 + (w + 1);
      *(u16x4*)(xrp2 + gran * 8 + e0) = pk;
    }
  } else {
    const int rb = bid - 3584;
    int idx = rb * 256 + tid;
    wor[idx] = bf16rne(wo[idx]);
    if (rb < 2) {
      sums[idx] = 0.f;
      sumsq[idx] = 0.f;
    }
  }
}

// ---------------------------------------------------------------------------
// Kernel 1: 3x3 conv via mfma_f32_32x32x16_bf16, ONE WAVE per block (R12).
// Block output: 64co x 64n (2h x 32w). K loop: 32 half-chunks of 16 ci
// (frag plane = hi = lane>>5). LDS = Wl 18KB + Xl 4.4KB = 22.4 KB ->
// 7 blocks/CU (vs R11 58.9KB/2). Grid (16,24,8) = 3072 single-wave blocks.
// Staging: 18 W + 6 X contiguous-1KB DMA instrs per iter, one wave.
// A/B frag (R11-verified): [m|n=lane&31][k=hi*8+e]. C/D (m74/m101):
// col=lane&31, row=(reg&3)+8*(reg>>2)+4*hi. Same 0.031 B/FLOP as R11.
// ---------------------------------------------------------------------------
__global__ __launch_bounds__(64) void conv3x3_mfma(
    const unsigned short* __restrict__ wqr2,
    const unsigned short* __restrict__ xrp2,
    unsigned short* __restrict__ qt, unsigned short* __restrict__ kt,
    unsigned short* __restrict__ vt, float* __restrict__ rqn,
    float* __restrict__ rkn) {
  __shared__ __align__(16) unsigned short Wl[1152 * 8];  // 18432 B [pl:2][t][co]
  __shared__ __align__(16) unsigned short Xl[272 * 8];   // 4352 B [pl:2][4hh*34wi]

  const int lane = threadIdx.x;
  const int l31 = lane & 31;
  const int hi = lane >> 5;
  const int h0 = blockIdx.x * 2;  // 2 h-rows of output per block
  const int co0 = blockIdx.y * 64;
  const int b = blockIdx.z;

  f32x16 acc[2][2];  // [ma co-tile][nbt n-tile]
  for (int ma = 0; ma < 2; ++ma)
    for (int nbt = 0; nbt < 2; ++nbt)
#pragma unroll
      for (int e = 0; e < 16; ++e) acc[ma][nbt][e] = 0.f;

  for (int kc = 0; kc < 32; ++kc) {
    const int ci0c = kc >> 1;
    const int half = kc & 1;
    __syncthreads();  // prior iter's reads done (single wave: cheap)
    // W half-chunk: 1152 contiguous granules = 18 x 1KB.
    const unsigned short* wsrc =
        wqr2 + (size_t)(ci0c * 24 + (co0 >> 6)) * 18432 + (size_t)half * 9216;
#pragma unroll
    for (int c = 0; c < 18; ++c)
      async16(wsrc + (size_t)c * 512 + lane * 8, Wl + (size_t)c * 512);
    // X: 2 planes (c4 = half*2+q), 4 halo rows (h0..h0+3) = 136 granules each:
    // 2 full 1KB + 1 overlapped tail (gran 72..135) per plane.
#pragma unroll
    for (int q = 0; q < 2; ++q) {
      const unsigned short* xsrc =
          xrp2 +
          ((size_t)((ci0c * 4 + half * 2 + q) * 8 + b) * 1156 + h0 * 34) * 8;
      async16(xsrc + (size_t)0 * 512 + lane * 8, Xl + (size_t)(q * 136) * 8);
      async16(xsrc + (size_t)1 * 512 + lane * 8, Xl + (size_t)(q * 136 + 64) * 8);
      async16(xsrc + (size_t)72 * 8 + lane * 8, Xl + (size_t)(q * 136 + 72) * 8);
    }
    __syncthreads();  // drains vmcnt before frag reads

#pragma unroll
    for (int t = 0; t < 9; ++t) {
      const int ky = t / 3, kx = t - ky * 3;
      bf16x8 af[2], bfr[2];
#pragma unroll
      for (int ma = 0; ma < 2; ++ma)
        af[ma] = *(const bf16x8*)(
            Wl + (size_t)((hi * 9 + t) * 64 + ma * 32 + l31) * 8);
#pragma unroll
      for (int nbt = 0; nbt < 2; ++nbt) {
        int n = nbt * 32 + l31;
        int hh = (n >> 5) + ky;   // 0..3
        int wi = (n & 31) + kx;   // 0..33
        bfr[nbt] = *(const bf16x8*)(Xl + (size_t)(hi * 136 + hh * 34 + wi) * 8);
      }
#pragma unroll
      for (int ma = 0; ma < 2; ++ma)
#pragma unroll
        for (int nbt = 0; nbt < 2; ++nbt)
          acc[ma][nbt] = __builtin_amdgcn_mfma_f32_32x32x16_bf16(
              af[ma], bfr[nbt], acc[ma][nbt], 0, 0, 0);
    }
  }

  // Epilogue. row(d) = (reg&3)+8*(reg>>2)+4*hi; col(n) = l31.
  const int sec = co0 >> 9;
  const int g = (co0 & 511) >> 6;
  const int bg = b * 8 + g;
  if (sec < 2) {
    unsigned short* dst = (sec == 0) ? qt : kt;
#pragma unroll
    for (int ma = 0; ma < 2; ++ma)
#pragma unroll
      for (int nbt = 0; nbt < 2; ++nbt) {
        int n = nbt * 32 + l31;
        int p = (h0 + (n >> 5)) * 32 + (n & 31);
#pragma unroll
        for (int g4 = 0; g4 < 4; ++g4) {
          u16x4 pk;
#pragma unroll
          for (int r2 = 0; r2 < 4; ++r2)
            pk[r2] = bf16rne(acc[ma][nbt][g4 * 4 + r2]);
          int d = ma * 32 + g4 * 8 + hi * 4;
          *(u16x4*)(dst + ((size_t)bg * 1024 + p) * 64 + d) = pk;
        }
      }
    // Reciprocal row norms: whole head d=64 in this wave.
    float sn[2];
#pragma unroll
    for (int nbt = 0; nbt < 2; ++nbt) {
      float s = 0.f;
#pragma unroll
      for (int ma = 0; ma < 2; ++ma)
#pragma unroll
        for (int e = 0; e < 16; ++e)
          s = fmaf(acc[ma][nbt][e], acc[ma][nbt][e], s);
      s += __shfl_down(s, 32);
      sn[nbt] = s;
    }
    if (lane < 32) {
      float* ndst = (sec == 0) ? rqn : rkn;
#pragma unroll
      for (int nbt = 0; nbt < 2; ++nbt) {
        int n = nbt * 32 + lane;
        int p = (h0 + (n >> 5)) * 32 + (n & 31);
        ndst[bg * 1024 + p] = rsqrtf(sn[nbt] + SMOOTH);
      }
    }
  } else {
#pragma unroll
    for (int ma = 0; ma < 2; ++ma)
#pragma unroll
      for (int nbt = 0; nbt < 2; ++nbt) {
        int n = nbt * 32 + l31;
        int p = (h0 + (n >> 5)) * 32 + (n & 31);
#pragma unroll
        for (int reg = 0; reg < 16; ++reg) {
          int d = ma * 32 + (reg & 3) + 8 * (reg >> 2) + 4 * hi;
          vt[((size_t)bg * 64 + d) * 1024 + p] = bf16rne(acc[ma][nbt][reg]);
        }
      }
  }
}

// ---------------------------------------------------------------------------
// Kernel 3: attention, bf16 MFMA (unchanged from R10/R11).
// ---------------------------------------------------------------------------
__global__ __launch_bounds__(256) void attn_mfma(
    const unsigned short* __restrict__ qt, const unsigned short* __restrict__ kt,
    const unsigned short* __restrict__ vt, const float* __restrict__ rqn,
    const float* __restrict__ rkn, unsigned short* __restrict__ aob) {
  __shared__ __align__(16) unsigned short Kl[64 * 72];
  __shared__ __align__(16) unsigned short Vl[64 * 72];
  __shared__ __align__(16) unsigned short Sl[64 * 72];

  const int tid = threadIdx.x;
  const int lane = tid & 63, wave = tid >> 6;
  const int l15 = lane & 15, quad = lane >> 4;
  const int bg = blockIdx.x;
  const int i0 = blockIdx.y * 64;
  const int iw = i0 + wave * 16;
  const int b = bg >> 3, g = bg & 7;

  bf16x8 qf[2];
#pragma unroll
  for (int ks = 0; ks < 2; ++ks)
    qf[ks] = *(const bf16x8*)(
        qt + ((size_t)bg * 1024 + iw + l15) * 64 + ks * 32 + quad * 8);

  float rq[4];
#pragma unroll
  for (int r = 0; r < 4; ++r) rq[r] = rqn[bg * 1024 + iw + quad * 4 + r];

  f32x4 oacc[4];
  for (int nf = 0; nf < 4; ++nf) oacc[nf] = (f32x4){0.f, 0.f, 0.f, 0.f};

  unsigned short* Sw = Sl + wave * 16 * 72;

  for (int jt = 0; jt < 16; ++jt) {
    const int j0 = jt * 64;
    __syncthreads();
    for (int idx = tid; idx < 512; idx += 256) {
      int c8 = idx & 7, row = idx >> 3;
      *(u32x4*)(Kl + row * 72 + c8 * 8) =
          *(const u32x4*)(kt + ((size_t)bg * 1024 + j0 + row) * 64 + c8 * 8);
      *(u32x4*)(Vl + row * 72 + c8 * 8) =
          *(const u32x4*)(vt + ((size_t)bg * 64 + row) * 1024 + j0 + c8 * 8);
    }
    __syncthreads();

    f32x4 sacc[4];
    for (int nb = 0; nb < 4; ++nb) sacc[nb] = (f32x4){0.f, 0.f, 0.f, 0.f};
#pragma unroll
    for (int ks = 0; ks < 2; ++ks) {
#pragma unroll
      for (int nb = 0; nb < 4; ++nb) {
        bf16x8 kf = *(const bf16x8*)(Kl + (l15 + 16 * nb) * 72 + ks * 32 + quad * 8);
        sacc[nb] = __builtin_amdgcn_mfma_f32_16x16x32_bf16(
            qf[ks], kf, sacc[nb], 0, 0, 0);
      }
    }

#pragma unroll
    for (int nb = 0; nb < 4; ++nb) {
      float rk = rkn[bg * 1024 + j0 + l15 + 16 * nb];
#pragma unroll
      for (int r = 0; r < 4; ++r) {
        float s = sacc[nb][r] * (rq[r] * rk);
        Sw[(quad * 4 + r) * 72 + l15 + 16 * nb] = bf16rne(s);
      }
    }
#pragma unroll
    for (int ks2 = 0; ks2 < 2; ++ks2) {
      bf16x8 sa = *(const bf16x8*)(Sw + l15 * 72 + ks2 * 32 + quad * 8);
#pragma unroll
      for (int nf = 0; nf < 4; ++nf) {
        bf16x8 vb = *(const bf16x8*)(Vl + (l15 + 16 * nf) * 72 + ks2 * 32 + quad * 8);
        oacc[nf] = __builtin_amdgcn_mfma_f32_16x16x32_bf16(sa, vb, oacc[nf], 0, 0, 0);
      }
    }
  }

#pragma unroll
  for (int nf = 0; nf < 4; ++nf)
#pragma unroll
    for (int r = 0; r < 4; ++r) {
      int i = iw + quad * 4 + r;
      int d = l15 + 16 * nf;
      aob[((size_t)(b * 1024) + i) * 512 + g * 64 + d] = bf16rne(oacc[nf][r]);
    }
}

// ---------------------------------------------------------------------------
// Kernel 4: 1x1 conv bf16 MFMA + BN stats (unchanged).
// ---------------------------------------------------------------------------
__global__ __launch_bounds__(256) void conv1x1_mfma(
    const unsigned short* __restrict__ wor, const unsigned short* __restrict__ aob,
    unsigned short* __restrict__ yb, float* __restrict__ sums,
    float* __restrict__ sumsq) {
  __shared__ __align__(16) unsigned short Wl[64 * 40];
  __shared__ __align__(16) unsigned short Bl[64 * 40];

  const int tid = threadIdx.x;
  const int lane = tid & 63, wave = tid >> 6;
  const int l15 = lane & 15, quad = lane >> 4;
  const int wco = (wave & 1) * 32;
  const int wp = (wave >> 1) * 32;
  const int p0 = blockIdx.x * 64;
  const int co0 = blockIdx.y * 64;
  const int b = blockIdx.z;

  f32x4 acc[2][2];
  for (int ma = 0; ma < 2; ++ma)
    for (int nb = 0; nb < 2; ++nb) acc[ma][nb] = (f32x4){0.f, 0.f, 0.f, 0.f};

  for (int ci0 = 0; ci0 < 512; ci0 += 32) {
    __syncthreads();
    {
      int c4 = tid & 3, co = tid >> 2;
      *(u32x4*)(Wl + co * 40 + c4 * 8) =
          *(const u32x4*)(wor + (size_t)(co0 + co) * 512 + ci0 + c4 * 8);
      *(u32x4*)(Bl + co * 40 + c4 * 8) =
          *(const u32x4*)(aob + ((size_t)(b * 1024) + p0 + co) * 512 + ci0 + c4 * 8);
    }
    __syncthreads();

    bf16x8 af[2], bf[2];
#pragma unroll
    for (int ma = 0; ma < 2; ++ma)
      af[ma] = *(const bf16x8*)(Wl + (wco + ma * 16 + l15) * 40 + quad * 8);
#pragma unroll
    for (int nb = 0; nb < 2; ++nb)
      bf[nb] = *(const bf16x8*)(Bl + (wp + nb * 16 + l15) * 40 + quad * 8);
#pragma unroll
    for (int ma = 0; ma < 2; ++ma)
#pragma unroll
      for (int nb = 0; nb < 2; ++nb)
        acc[ma][nb] = __builtin_amdgcn_mfma_f32_16x16x32_bf16(
            af[ma], bf[nb], acc[ma][nb], 0, 0, 0);
  }

#pragma unroll
  for (int ma = 0; ma < 2; ++ma)
#pragma unroll
    for (int r = 0; r < 4; ++r) {
      int co = co0 + wco + ma * 16 + quad * 4 + r;
      float s1 = 0.f, s2 = 0.f;
#pragma unroll
      for (int nb = 0; nb < 2; ++nb) {
        float v = acc[ma][nb][r];
        yb[((size_t)(b * 512) + co) * 1024 + p0 + wp + nb * 16 + l15] = bf16rne(v);
        s1 += v;
        s2 = fmaf(v, v, s2);
      }
      for (int off = 8; off >= 1; off >>= 1) {
        s1 += __shfl_down(s1, off, 16);
        s2 += __shfl_down(s2, off, 16);
      }
      if (l15 == 0) {
        atomicAdd(&sums[co], s1);
        atomicAdd(&sumsq[co], s2);
      }
    }
}

// ---------------------------------------------------------------------------
// Kernel 5: BatchNorm + ReLU (unchanged).
// ---------------------------------------------------------------------------
__global__ void bn_kernel(const unsigned short* __restrict__ yb,
                          const float* __restrict__ sums,
                          const float* __restrict__ sumsq,
                          const float* __restrict__ gamma,
                          const float* __restrict__ beta,
                          float* __restrict__ out) {
  int idx = blockIdx.x * 256 + threadIdx.x;
  int c = (idx >> 8) & 511;
  u16x4 vb = *(const u16x4*)(yb + (size_t)idx * 4);
  float mean = sums[c] * (1.f / 8192.f);
  float var = sumsq[c] * (1.f / 8192.f) - mean * mean;
  float sc = gamma[c] * rsqrtf(var + BN_EPS);
  float sh = beta[c] - mean * sc;
  float4 r;
  r.x = fmaxf(0.f, fmaf(b2f(vb[0]), sc, sh));
  r.y = fmaxf(0.f, fmaf(b2f(vb[1]), sc, sh));
  r.z = fmaxf(0.f, fmaf(b2f(vb[2]), sc, sh));
  r.w = fmaxf(0.f, fmaf(b2f(vb[3]), sc, sh));
  ((float4*)out)[idx] = r;
}

// ---------------------------------------------------------------------------
extern "C" void kernel_launch(void* const* d_in, const int* in_sizes, int n_in,
                              void* d_out, int out_size, void* d_ws,
                              size_t ws_size, hipStream_t stream) {
  const float* x = (const float*)d_in[0];
  const float* wq = (const float*)d_in[1];
  const float* wo = (const float*)d_in[2];
  const float* gamma = (const float*)d_in[3];
  const float* beta = (const float*)d_in[4];
  float* out = (float*)d_out;

  unsigned short* qt = (unsigned short*)d_ws;          // [64][1024][64]
  unsigned short* kt = qt + (size_t)4194304;
  unsigned short* vt = kt + (size_t)4194304;           // [64][64][1024]
  unsigned short* aob = vt + (size_t)4194304;          // [8][1024][512]
  unsigned short* wqr2 = aob + (size_t)4194304;        // [16][24][4][9][64][8]
  unsigned short* wor = wqr2 + (size_t)7077888;        // [512][512]
  unsigned short* xrp2 = wor + (size_t)262144;         // [16][4][8][34][34][8]+pad
  float* rqn = (float*)(xrp2 + (size_t)4736000);       // [64][1024]
  float* rkn = rqn + 65536;
  unsigned short* yb = (unsigned short*)(rkn + 65536); // [8][512][1024] bf16
  float* sums = (float*)(yb + (size_t)4194304);
  float* sumsq = sums + 512;

  hipMemsetAsync(xrp2, 0, (size_t)4736000 * 2, stream);
  prep_kernel<<<dim3(4608), 256, 0, stream>>>(wq, wqr2, x, xrp2, wo, wor, sums,
                                              sumsq);
  conv3x3_mfma<<<dim3(16, 24, 8), 64, 0, stream>>>(wqr2, xrp2, qt, kt, vt, rqn,
                                                   rkn);
  attn_mfma<<<dim3(64, 16), 256, 0, stream>>>(qt, kt, vt, rqn, rkn, aob);
  conv1x1_mfma<<<dim3(16, 8, 8), 256, 0, stream>>>(wor, aob, yb, sums, sumsq);
  bn_kernel<<<dim3(4096), 256, 0, stream>>>(yb, sums, sumsq, gamma, beta, out);
}

// Round 13
// 294.387 us; speedup vs baseline: 1.1085x; 1.1085x over previous
//
#include <hip/hip_runtime.h>
#include <math.h>

// x: [8,512,32,32] fp32 | W_qkv: [1536,512,3,3] fp32 | W_out: [512,512,1,1]
// gamma/beta: [512] | out: [8,512,32,32] fp32
// G=8 heads, D=64 head dim, N=1024 seq (h*w), B=8

#define SMOOTH 1e-4f
#define BN_EPS 1e-5f

typedef __attribute__((ext_vector_type(8))) short bf16x8;
typedef __attribute__((ext_vector_type(8))) unsigned short u16x8;
typedef __attribute__((ext_vector_type(4))) float f32x4;
typedef __attribute__((ext_vector_type(4))) unsigned int u32x4;
typedef __attribute__((ext_vector_type(4))) unsigned short u16x4;

__device__ inline unsigned short bf16rne(float f) {
  unsigned int u = __float_as_uint(f);
  u += 0x7fff + ((u >> 16) & 1);
  return (unsigned short)(u >> 16);
}
__device__ inline float b2f(unsigned short u) {
  return __uint_as_float((unsigned int)u << 16);
}

// Async 16B global->LDS DMA (gfx950). LDS dest = wave-uniform base + lane*16.
// RULE (R8): lane gptr MUST be base + lane*16 (contiguous 1KB/wave),
// else ~4-5x HBM overfetch.
typedef __attribute__((address_space(1))) void gvoid;
typedef __attribute__((address_space(3))) void lvoid;
__device__ __forceinline__ void async16(const void* g, void* l) {
  __builtin_amdgcn_global_load_lds((gvoid*)g, (lvoid*)l, 16, 0, 0);
}

// ---------------------------------------------------------------------------
// prep_kernel: merged repacks (R11 version — saved ~15us of non-conv time).
//  [0,3072):    W_qkv [co][ci][3][3] fp32 -> wqr2 [ci0c][cotile][c4][t][co][e]
//  [3072,3584): x [b][ci][p] fp32 -> xrp2 [ci0c][c4][b][34][34][e] (padded)
//  [3584,4608): W_out fp32 -> bf16; first 2 blocks zero BN stats
// ---------------------------------------------------------------------------
__global__ void prep_kernel(const float* __restrict__ wq,
                            unsigned short* __restrict__ wqr2,
                            const float* __restrict__ x,
                            unsigned short* __restrict__ xrp2,
                            const float* __restrict__ wo,
                            unsigned short* __restrict__ wor,
                            float* __restrict__ sums,
                            float* __restrict__ sumsq) {
  __shared__ float Sh[64 * 132];
  const int tid = threadIdx.x;
  const int bid = blockIdx.x;
  if (bid < 3072) {
    const size_t pair0 = (size_t)bid * 256;
    for (int off = tid; off < 576; off += 256)
      *(float4*)(Sh + off * 4) = *(const float4*)(wq + pair0 * 9 + off * 4);
    __syncthreads();
    const int co = (int)(pair0 >> 9);
    const int ciBase = (int)(pair0 & 511);
    const int cotile = co >> 6, co_l = co & 63;
    for (int idx = tid; idx < 288; idx += 256) {
      int t = idx >> 5;
      int oct = idx & 31;
      int ci = ciBase + oct * 8;
      int ci0c = ci >> 5, c4 = oct & 3;
      u16x8 pk;
#pragma unroll
      for (int e = 0; e < 8; ++e) pk[e] = bf16rne(Sh[(oct * 8 + e) * 9 + t]);
      size_t o = (size_t)(ci0c * 24 + cotile) * 18432 +
                 (size_t)((c4 * 9 + t) * 64 + co_l) * 8;
      *(u16x8*)(wqr2 + o) = pk;
    }
  } else if (bid < 3584) {
    const int bx = bid - 3072;
    const int p0 = (bx & 7) * 128;
    const int ci0 = ((bx >> 3) & 7) * 64;
    const int b = bx >> 6;
    for (int k = 0; k < 8; ++k) {
      int idx = tid + k * 256;
      int c4 = idx & 31, row = idx >> 5;
      *(float4*)(Sh + row * 132 + c4 * 4) =
          *(const float4*)(x + ((size_t)(b * 512 + ci0 + row)) * 1024 + p0 + c4 * 4);
    }
    __syncthreads();
    const int pl = tid >> 1, half = tid & 1;
    const int p = p0 + pl;
    const int h = p >> 5, w = p & 31;
#pragma unroll
    for (int v = 0; v < 8; ++v) {
      u16x4 pk;
#pragma unroll
      for (int e = 0; e < 4; ++e)
        pk[e] = bf16rne(Sh[(half * 32 + v * 4 + e) * 132 + pl]);
      int cc = ci0 + half * 32 + v * 4;
      int ci0c = cc >> 5, c4 = (cc >> 3) & 3, e0 = cc & 7;
      size_t gran =
          (size_t)((ci0c * 4 + c4) * 8 + b) * 1156 + (h + 1) * 34 + (w + 1);
      *(u16x4*)(xrp2 + gran * 8 + e0) = pk;
    }
  } else {
    const int rb = bid - 3584;
    int idx = rb * 256 + tid;
    wor[idx] = bf16rne(wo[idx]);
    if (rb < 2) {
      sums[idx] = 0.f;
      sumsq[idx] = 0.f;
    }
  }
}

// ---------------------------------------------------------------------------
// Kernel 1: 3x3 conv bf16 MFMA implicit GEMM — R10 version VERBATIM (the
// measured optimum of this family: 108us, MfmaUtil 50%, 0 bank conflicts).
// Block 64co x 128n (4h x 32w), 4 waves of 32co x 64n, 16x16x32 MFMA,
// K-chunks of 32 ci. LDS plane layouts [c4][t][co] / [c4][hh*34+wi];
// staging = contiguous-1KB async DMA. 53.8KB LDS -> ~3 blocks/CU.
// R11 attempts to beat it (32x32x16, bigger/smaller blocks) lost to
// occupancy (R11: 2 blocks/CU) or W-staging amortization (R12: 4x traffic).
// Fused epilogue: reciprocal row norms rqn/rkn = rsqrt(sum+SMOOTH).
// ---------------------------------------------------------------------------
__global__ __launch_bounds__(256) void conv3x3_mfma(
    const unsigned short* __restrict__ wqr2,
    const unsigned short* __restrict__ xrp2,
    unsigned short* __restrict__ qt, unsigned short* __restrict__ kt,
    unsigned short* __restrict__ vt, float* __restrict__ rqn,
    float* __restrict__ rkn) {
  __shared__ __align__(16) unsigned short Wl[2304 * 8];     // 36864 B
  __shared__ __align__(16) unsigned short Xl[4 * 256 * 8];  // 16384 B
  __shared__ float Snl[128];                                // norm partials

  const int tid = threadIdx.x;
  const int lane = tid & 63;
  const int wave = tid >> 6;
  const int wco = (wave & 1) * 32;
  const int wn = (wave >> 1) * 64;
  const int l15 = lane & 15;
  const int quad = lane >> 4;
  const int h0 = blockIdx.x * 4;
  const int co0 = blockIdx.y * 64;
  const int b = blockIdx.z;

  f32x4 acc[2][4];
  for (int ma = 0; ma < 2; ++ma)
    for (int nb = 0; nb < 4; ++nb) acc[ma][nb] = (f32x4){0.f, 0.f, 0.f, 0.f};

  for (int ci0 = 0; ci0 < 512; ci0 += 32) {
    const int ci0c = ci0 >> 5;
    __syncthreads();  // prior iter's readers done
    // W: 36 x 1KB contiguous wave reads (9 per wave).
    const unsigned short* wsrc =
        wqr2 + (size_t)(ci0c * 24 + (co0 >> 6)) * 18432;
    {
      int cbase = wave * 9;
#pragma unroll
      for (int j = 0; j < 9; ++j) {
        int c = cbase + j;
        async16(wsrc + (size_t)c * 512 + lane * 8, Wl + (size_t)c * 512);
      }
    }
    // X: plane wave; 4 x 1KB contiguous reads (last overlaps 52 junk
    // granules into unread LDS slots; xrp2 is padded at the end).
    const unsigned short* xsrc =
        xrp2 + ((size_t)((ci0c * 4 + wave) * 8 + b) * 1156 + h0 * 34) * 8;
#pragma unroll
    for (int j = 0; j < 4; ++j)
      async16(xsrc + (size_t)j * 512 + lane * 8,
              Xl + (size_t)(wave * 256 + j * 64) * 8);
    __syncthreads();  // drains vmcnt before frag reads

#pragma unroll
    for (int t = 0; t < 9; ++t) {
      const int ky = t / 3, kx = t - ky * 3;
      bf16x8 af[2], bfr[4];
#pragma unroll
      for (int ma = 0; ma < 2; ++ma)
        af[ma] = *(const bf16x8*)(
            Wl + (size_t)((quad * 9 + t) * 64 + wco + ma * 16 + l15) * 8);
#pragma unroll
      for (int nb = 0; nb < 4; ++nb) {
        int n = wn + nb * 16 + l15;
        int hh = (n >> 5) + ky;
        int wi = (n & 31) + kx;
        bfr[nb] = *(const bf16x8*)(Xl + (size_t)(quad * 256 + hh * 34 + wi) * 8);
      }
#pragma unroll
      for (int ma = 0; ma < 2; ++ma)
#pragma unroll
        for (int nb = 0; nb < 4; ++nb)
          acc[ma][nb] = __builtin_amdgcn_mfma_f32_16x16x32_bf16(
              af[ma], bfr[nb], acc[ma][nb], 0, 0, 0);
    }
  }

  // Epilogue: C/D layout col(n)=lane&15, row(m)=quad*4+reg.
  const int sec = co0 >> 9;
  const int g = (co0 & 511) >> 6;
  const int bg = b * 8 + g;
  if (sec < 2) {
    unsigned short* dst = (sec == 0) ? qt : kt;
#pragma unroll
    for (int ma = 0; ma < 2; ++ma)
#pragma unroll
      for (int nb = 0; nb < 4; ++nb) {
        int n = wn + nb * 16 + l15;
        int p = (h0 + (n >> 5)) * 32 + (n & 31);
        int db = wco + ma * 16 + quad * 4;
        u16x4 pk;
#pragma unroll
        for (int r = 0; r < 4; ++r) pk[r] = bf16rne(acc[ma][nb][r]);
        *(u16x4*)(dst + ((size_t)bg * 1024 + p) * 64 + db) = pk;
      }
    // Fused reciprocal row norms.
    float ps[4];
#pragma unroll
    for (int nb = 0; nb < 4; ++nb) {
      float s = 0.f;
#pragma unroll
      for (int ma = 0; ma < 2; ++ma)
#pragma unroll
        for (int r = 0; r < 4; ++r) s = fmaf(acc[ma][nb][r], acc[ma][nb][r], s);
      s += __shfl_down(s, 32);
      s += __shfl_down(s, 16);
      ps[nb] = s;  // valid in quad==0 lanes
    }
    if (wco == 0 && quad == 0)
#pragma unroll
      for (int nb = 0; nb < 4; ++nb) Snl[wn + nb * 16 + l15] = ps[nb];
    __syncthreads();
    if (wco == 32 && quad == 0) {
      float* ndst = (sec == 0) ? rqn : rkn;
#pragma unroll
      for (int nb = 0; nb < 4; ++nb) {
        int n = wn + nb * 16 + l15;
        int p = (h0 + (n >> 5)) * 32 + (n & 31);
        ndst[bg * 1024 + p] = rsqrtf(Snl[n] + ps[nb] + SMOOTH);
      }
    }
  } else {
#pragma unroll
    for (int ma = 0; ma < 2; ++ma)
#pragma unroll
      for (int nb = 0; nb < 4; ++nb) {
        int n = wn + nb * 16 + l15;
        int p = (h0 + (n >> 5)) * 32 + (n & 31);
#pragma unroll
        for (int r = 0; r < 4; ++r) {
          int d = wco + ma * 16 + quad * 4 + r;
          vt[((size_t)bg * 64 + d) * 1024 + p] = bf16rne(acc[ma][nb][r]);
        }
      }
  }
}

// ---------------------------------------------------------------------------
// Kernel 3: attention, bf16 MFMA. Block = 64 i x (b,g); 4 waves, 16 i each.
// Normalize: S = sacc * rqn_i * rkn_j (no rcp).
// ---------------------------------------------------------------------------
__global__ __launch_bounds__(256) void attn_mfma(
    const unsigned short* __restrict__ qt, const unsigned short* __restrict__ kt,
    const unsigned short* __restrict__ vt, const float* __restrict__ rqn,
    const float* __restrict__ rkn, unsigned short* __restrict__ aob) {
  __shared__ __align__(16) unsigned short Kl[64 * 72];
  __shared__ __align__(16) unsigned short Vl[64 * 72];
  __shared__ __align__(16) unsigned short Sl[64 * 72];

  const int tid = threadIdx.x;
  const int lane = tid & 63, wave = tid >> 6;
  const int l15 = lane & 15, quad = lane >> 4;
  const int bg = blockIdx.x;  // fastest -> same-bg blocks share XCD L2
  const int i0 = blockIdx.y * 64;
  const int iw = i0 + wave * 16;
  const int b = bg >> 3, g = bg & 7;

  bf16x8 qf[2];
#pragma unroll
  for (int ks = 0; ks < 2; ++ks)
    qf[ks] = *(const bf16x8*)(
        qt + ((size_t)bg * 1024 + iw + l15) * 64 + ks * 32 + quad * 8);

  float rq[4];
#pragma unroll
  for (int r = 0; r < 4; ++r) rq[r] = rqn[bg * 1024 + iw + quad * 4 + r];

  f32x4 oacc[4];
  for (int nf = 0; nf < 4; ++nf) oacc[nf] = (f32x4){0.f, 0.f, 0.f, 0.f};

  unsigned short* Sw = Sl + wave * 16 * 72;

  for (int jt = 0; jt < 16; ++jt) {
    const int j0 = jt * 64;
    __syncthreads();
    for (int idx = tid; idx < 512; idx += 256) {
      int c8 = idx & 7, row = idx >> 3;
      *(u32x4*)(Kl + row * 72 + c8 * 8) =
          *(const u32x4*)(kt + ((size_t)bg * 1024 + j0 + row) * 64 + c8 * 8);
      *(u32x4*)(Vl + row * 72 + c8 * 8) =
          *(const u32x4*)(vt + ((size_t)bg * 64 + row) * 1024 + j0 + c8 * 8);
    }
    __syncthreads();

    f32x4 sacc[4];
    for (int nb = 0; nb < 4; ++nb) sacc[nb] = (f32x4){0.f, 0.f, 0.f, 0.f};
#pragma unroll
    for (int ks = 0; ks < 2; ++ks) {
#pragma unroll
      for (int nb = 0; nb < 4; ++nb) {
        bf16x8 kf = *(const bf16x8*)(Kl + (l15 + 16 * nb) * 72 + ks * 32 + quad * 8);
        sacc[nb] = __builtin_amdgcn_mfma_f32_16x16x32_bf16(
            qf[ks], kf, sacc[nb], 0, 0, 0);
      }
    }

#pragma unroll
    for (int nb = 0; nb < 4; ++nb) {
      float rk = rkn[bg * 1024 + j0 + l15 + 16 * nb];
#pragma unroll
      for (int r = 0; r < 4; ++r) {
        float s = sacc[nb][r] * (rq[r] * rk);
        Sw[(quad * 4 + r) * 72 + l15 + 16 * nb] = bf16rne(s);
      }
    }
    // Sw is wave-private: lgkmcnt orders write->read, no barrier needed.
#pragma unroll
    for (int ks2 = 0; ks2 < 2; ++ks2) {
      bf16x8 sa = *(const bf16x8*)(Sw + l15 * 72 + ks2 * 32 + quad * 8);
#pragma unroll
      for (int nf = 0; nf < 4; ++nf) {
        bf16x8 vb = *(const bf16x8*)(Vl + (l15 + 16 * nf) * 72 + ks2 * 32 + quad * 8);
        oacc[nf] = __builtin_amdgcn_mfma_f32_16x16x32_bf16(sa, vb, oacc[nf], 0, 0, 0);
      }
    }
  }

#pragma unroll
  for (int nf = 0; nf < 4; ++nf)
#pragma unroll
    for (int r = 0; r < 4; ++r) {
      int i = iw + quad * 4 + r;
      int d = l15 + 16 * nf;
      aob[((size_t)(b * 1024) + i) * 512 + g * 64 + d] = bf16rne(oacc[nf][r]);
    }
}

// ---------------------------------------------------------------------------
// Kernel 4: 1x1 conv bf16 MFMA (M=512co, N=8192p, K=512ci) + BN stats.
// Block 64co x 64p (grid 1024 = 4/CU), 4 waves of 32co x 32p. y stored bf16.
// ---------------------------------------------------------------------------
__global__ __launch_bounds__(256) void conv1x1_mfma(
    const unsigned short* __restrict__ wor, const unsigned short* __restrict__ aob,
    unsigned short* __restrict__ yb, float* __restrict__ sums,
    float* __restrict__ sumsq) {
  __shared__ __align__(16) unsigned short Wl[64 * 40];
  __shared__ __align__(16) unsigned short Bl[64 * 40];

  const int tid = threadIdx.x;
  const int lane = tid & 63, wave = tid >> 6;
  const int l15 = lane & 15, quad = lane >> 4;
  const int wco = (wave & 1) * 32;
  const int wp = (wave >> 1) * 32;
  const int p0 = blockIdx.x * 64;
  const int co0 = blockIdx.y * 64;
  const int b = blockIdx.z;

  f32x4 acc[2][2];
  for (int ma = 0; ma < 2; ++ma)
    for (int nb = 0; nb < 2; ++nb) acc[ma][nb] = (f32x4){0.f, 0.f, 0.f, 0.f};

  for (int ci0 = 0; ci0 < 512; ci0 += 32) {
    __syncthreads();
    {
      int c4 = tid & 3, co = tid >> 2;
      *(u32x4*)(Wl + co * 40 + c4 * 8) =
          *(const u32x4*)(wor + (size_t)(co0 + co) * 512 + ci0 + c4 * 8);
      *(u32x4*)(Bl + co * 40 + c4 * 8) =
          *(const u32x4*)(aob + ((size_t)(b * 1024) + p0 + co) * 512 + ci0 + c4 * 8);
    }
    __syncthreads();

    bf16x8 af[2], bf[2];
#pragma unroll
    for (int ma = 0; ma < 2; ++ma)
      af[ma] = *(const bf16x8*)(Wl + (wco + ma * 16 + l15) * 40 + quad * 8);
#pragma unroll
    for (int nb = 0; nb < 2; ++nb)
      bf[nb] = *(const bf16x8*)(Bl + (wp + nb * 16 + l15) * 40 + quad * 8);
#pragma unroll
    for (int ma = 0; ma < 2; ++ma)
#pragma unroll
      for (int nb = 0; nb < 2; ++nb)
        acc[ma][nb] = __builtin_amdgcn_mfma_f32_16x16x32_bf16(
            af[ma], bf[nb], acc[ma][nb], 0, 0, 0);
  }

#pragma unroll
  for (int ma = 0; ma < 2; ++ma)
#pragma unroll
    for (int r = 0; r < 4; ++r) {
      int co = co0 + wco + ma * 16 + quad * 4 + r;
      float s1 = 0.f, s2 = 0.f;
#pragma unroll
      for (int nb = 0; nb < 2; ++nb) {
        float v = acc[ma][nb][r];
        yb[((size_t)(b * 512) + co) * 1024 + p0 + wp + nb * 16 + l15] = bf16rne(v);
        s1 += v;
        s2 = fmaf(v, v, s2);
      }
      for (int off = 8; off >= 1; off >>= 1) {
        s1 += __shfl_down(s1, off, 16);
        s2 += __shfl_down(s2, off, 16);
      }
      if (l15 == 0) {
        atomicAdd(&sums[co], s1);
        atomicAdd(&sumsq[co], s2);
      }
    }
}

// ---------------------------------------------------------------------------
// Kernel 5: BatchNorm (batch stats, biased var) + ReLU. bf16 in, fp32 out.
// ---------------------------------------------------------------------------
__global__ void bn_kernel(const unsigned short* __restrict__ yb,
                          const float* __restrict__ sums,
                          const float* __restrict__ sumsq,
                          const float* __restrict__ gamma,
                          const float* __restrict__ beta,
                          float* __restrict__ out) {
  int idx = blockIdx.x * 256 + threadIdx.x;
  int c = (idx >> 8) & 511;
  u16x4 vb = *(const u16x4*)(yb + (size_t)idx * 4);
  float mean = sums[c] * (1.f / 8192.f);
  float var = sumsq[c] * (1.f / 8192.f) - mean * mean;
  float sc = gamma[c] * rsqrtf(var + BN_EPS);
  float sh = beta[c] - mean * sc;
  float4 r;
  r.x = fmaxf(0.f, fmaf(b2f(vb[0]), sc, sh));
  r.y = fmaxf(0.f, fmaf(b2f(vb[1]), sc, sh));
  r.z = fmaxf(0.f, fmaf(b2f(vb[2]), sc, sh));
  r.w = fmaxf(0.f, fmaf(b2f(vb[3]), sc, sh));
  ((float4*)out)[idx] = r;
}

// ---------------------------------------------------------------------------
extern "C" void kernel_launch(void* const* d_in, const int* in_sizes, int n_in,
                              void* d_out, int out_size, void* d_ws,
                              size_t ws_size, hipStream_t stream) {
  const float* x = (const float*)d_in[0];
  const float* wq = (const float*)d_in[1];
  const float* wo = (const float*)d_in[2];
  const float* gamma = (const float*)d_in[3];
  const float* beta = (const float*)d_in[4];
  float* out = (float*)d_out;

  unsigned short* qt = (unsigned short*)d_ws;          // [64][1024][64]
  unsigned short* kt = qt + (size_t)4194304;
  unsigned short* vt = kt + (size_t)4194304;           // [64][64][1024]
  unsigned short* aob = vt + (size_t)4194304;          // [8][1024][512]
  unsigned short* wqr2 = aob + (size_t)4194304;        // [16][24][4][9][64][8]
  unsigned short* wor = wqr2 + (size_t)7077888;        // [512][512]
  unsigned short* xrp2 = wor + (size_t)262144;         // [16][4][8][34][34][8]+pad
  float* rqn = (float*)(xrp2 + (size_t)4736000);       // [64][1024]
  float* rkn = rqn + 65536;
  unsigned short* yb = (unsigned short*)(rkn + 65536); // [8][512][1024] bf16
  float* sums = (float*)(yb + (size_t)4194304);
  float* sumsq = sums + 512;

  hipMemsetAsync(xrp2, 0, (size_t)4736000 * 2, stream);
  prep_kernel<<<dim3(4608), 256, 0, stream>>>(wq, wqr2, x, xrp2, wo, wor, sums,
                                              sumsq);
  conv3x3_mfma<<<dim3(8, 24, 8), 256, 0, stream>>>(wqr2, xrp2, qt, kt, vt, rqn,
                                                   rkn);
  attn_mfma<<<dim3(64, 16), 256, 0, stream>>>(qt, kt, vt, rqn, rkn, aob);
  conv1x1_mfma<<<dim3(16, 8, 8), 256, 0, stream>>>(wor, aob, yb, sums, sumsq);
  bn_kernel<<<dim3(4096), 256, 0, stream>>>(yb, sums, sumsq, gamma, beta, out);
}

// Round 14
// 291.500 us; speedup vs baseline: 1.1195x; 1.0099x over previous
//
#include <hip/hip_runtime.h>
#include <math.h>

// x: [8,512,32,32] fp32 | W_qkv: [1536,512,3,3] fp32 | W_out: [512,512,1,1]
// gamma/beta: [512] | out: [8,512,32,32] fp32
// G=8 heads, D=64 head dim, N=1024 seq (h*w), B=8

#define SMOOTH 1e-4f
#define BN_EPS 1e-5f

typedef __attribute__((ext_vector_type(8))) short bf16x8;
typedef __attribute__((ext_vector_type(8))) unsigned short u16x8;
typedef __attribute__((ext_vector_type(4))) float f32x4;
typedef __attribute__((ext_vector_type(4))) unsigned int u32x4;
typedef __attribute__((ext_vector_type(4))) unsigned short u16x4;

__device__ inline unsigned short bf16rne(float f) {
  unsigned int u = __float_as_uint(f);
  u += 0x7fff + ((u >> 16) & 1);
  return (unsigned short)(u >> 16);
}
__device__ inline float b2f(unsigned short u) {
  return __uint_as_float((unsigned int)u << 16);
}

// Async 16B global->LDS DMA (gfx950). LDS dest = wave-uniform base + lane*16.
// RULE (R8): lane gptr MUST be base + lane*16 (contiguous 1KB/wave),
// else ~4-5x HBM overfetch.
typedef __attribute__((address_space(1))) void gvoid;
typedef __attribute__((address_space(3))) void lvoid;
__device__ __forceinline__ void async16(const void* g, void* l) {
  __builtin_amdgcn_global_load_lds((gvoid*)g, (lvoid*)l, 16, 0, 0);
}

// ---------------------------------------------------------------------------
// prep_kernel: merged repacks (unchanged from R13).
// ---------------------------------------------------------------------------
__global__ void prep_kernel(const float* __restrict__ wq,
                            unsigned short* __restrict__ wqr2,
                            const float* __restrict__ x,
                            unsigned short* __restrict__ xrp2,
                            const float* __restrict__ wo,
                            unsigned short* __restrict__ wor,
                            float* __restrict__ sums,
                            float* __restrict__ sumsq) {
  __shared__ float Sh[64 * 132];
  const int tid = threadIdx.x;
  const int bid = blockIdx.x;
  if (bid < 3072) {
    const size_t pair0 = (size_t)bid * 256;
    for (int off = tid; off < 576; off += 256)
      *(float4*)(Sh + off * 4) = *(const float4*)(wq + pair0 * 9 + off * 4);
    __syncthreads();
    const int co = (int)(pair0 >> 9);
    const int ciBase = (int)(pair0 & 511);
    const int cotile = co >> 6, co_l = co & 63;
    for (int idx = tid; idx < 288; idx += 256) {
      int t = idx >> 5;
      int oct = idx & 31;
      int ci = ciBase + oct * 8;
      int ci0c = ci >> 5, c4 = oct & 3;
      u16x8 pk;
#pragma unroll
      for (int e = 0; e < 8; ++e) pk[e] = bf16rne(Sh[(oct * 8 + e) * 9 + t]);
      size_t o = (size_t)(ci0c * 24 + cotile) * 18432 +
                 (size_t)((c4 * 9 + t) * 64 + co_l) * 8;
      *(u16x8*)(wqr2 + o) = pk;
    }
  } else if (bid < 3584) {
    const int bx = bid - 3072;
    const int p0 = (bx & 7) * 128;
    const int ci0 = ((bx >> 3) & 7) * 64;
    const int b = bx >> 6;
    for (int k = 0; k < 8; ++k) {
      int idx = tid + k * 256;
      int c4 = idx & 31, row = idx >> 5;
      *(float4*)(Sh + row * 132 + c4 * 4) =
          *(const float4*)(x + ((size_t)(b * 512 + ci0 + row)) * 1024 + p0 + c4 * 4);
    }
    __syncthreads();
    const int pl = tid >> 1, half = tid & 1;
    const int p = p0 + pl;
    const int h = p >> 5, w = p & 31;
#pragma unroll
    for (int v = 0; v < 8; ++v) {
      u16x4 pk;
#pragma unroll
      for (int e = 0; e < 4; ++e)
        pk[e] = bf16rne(Sh[(half * 32 + v * 4 + e) * 132 + pl]);
      int cc = ci0 + half * 32 + v * 4;
      int ci0c = cc >> 5, c4 = (cc >> 3) & 3, e0 = cc & 7;
      size_t gran =
          (size_t)((ci0c * 4 + c4) * 8 + b) * 1156 + (h + 1) * 34 + (w + 1);
      *(u16x4*)(xrp2 + gran * 8 + e0) = pk;
    }
  } else {
    const int rb = bid - 3584;
    int idx = rb * 256 + tid;
    wor[idx] = bf16rne(wo[idx]);
    if (rb < 2) {
      sums[idx] = 0.f;
      sumsq[idx] = 0.f;
    }
  }
}

// ---------------------------------------------------------------------------
// Kernel 1: 3x3 conv bf16 MFMA implicit GEMM — R10/R13 version VERBATIM
// (measured optimum: 107us, MfmaUtil 50%, 0 bank conflicts, LDS-port bound).
// ---------------------------------------------------------------------------
__global__ __launch_bounds__(256) void conv3x3_mfma(
    const unsigned short* __restrict__ wqr2,
    const unsigned short* __restrict__ xrp2,
    unsigned short* __restrict__ qt, unsigned short* __restrict__ kt,
    unsigned short* __restrict__ vt, float* __restrict__ rqn,
    float* __restrict__ rkn) {
  __shared__ __align__(16) unsigned short Wl[2304 * 8];     // 36864 B
  __shared__ __align__(16) unsigned short Xl[4 * 256 * 8];  // 16384 B
  __shared__ float Snl[128];                                // norm partials

  const int tid = threadIdx.x;
  const int lane = tid & 63;
  const int wave = tid >> 6;
  const int wco = (wave & 1) * 32;
  const int wn = (wave >> 1) * 64;
  const int l15 = lane & 15;
  const int quad = lane >> 4;
  const int h0 = blockIdx.x * 4;
  const int co0 = blockIdx.y * 64;
  const int b = blockIdx.z;

  f32x4 acc[2][4];
  for (int ma = 0; ma < 2; ++ma)
    for (int nb = 0; nb < 4; ++nb) acc[ma][nb] = (f32x4){0.f, 0.f, 0.f, 0.f};

  for (int ci0 = 0; ci0 < 512; ci0 += 32) {
    const int ci0c = ci0 >> 5;
    __syncthreads();  // prior iter's readers done
    const unsigned short* wsrc =
        wqr2 + (size_t)(ci0c * 24 + (co0 >> 6)) * 18432;
    {
      int cbase = wave * 9;
#pragma unroll
      for (int j = 0; j < 9; ++j) {
        int c = cbase + j;
        async16(wsrc + (size_t)c * 512 + lane * 8, Wl + (size_t)c * 512);
      }
    }
    const unsigned short* xsrc =
        xrp2 + ((size_t)((ci0c * 4 + wave) * 8 + b) * 1156 + h0 * 34) * 8;
#pragma unroll
    for (int j = 0; j < 4; ++j)
      async16(xsrc + (size_t)j * 512 + lane * 8,
              Xl + (size_t)(wave * 256 + j * 64) * 8);
    __syncthreads();  // drains vmcnt before frag reads

#pragma unroll
    for (int t = 0; t < 9; ++t) {
      const int ky = t / 3, kx = t - ky * 3;
      bf16x8 af[2], bfr[4];
#pragma unroll
      for (int ma = 0; ma < 2; ++ma)
        af[ma] = *(const bf16x8*)(
            Wl + (size_t)((quad * 9 + t) * 64 + wco + ma * 16 + l15) * 8);
#pragma unroll
      for (int nb = 0; nb < 4; ++nb) {
        int n = wn + nb * 16 + l15;
        int hh = (n >> 5) + ky;
        int wi = (n & 31) + kx;
        bfr[nb] = *(const bf16x8*)(Xl + (size_t)(quad * 256 + hh * 34 + wi) * 8);
      }
#pragma unroll
      for (int ma = 0; ma < 2; ++ma)
#pragma unroll
        for (int nb = 0; nb < 4; ++nb)
          acc[ma][nb] = __builtin_amdgcn_mfma_f32_16x16x32_bf16(
              af[ma], bfr[nb], acc[ma][nb], 0, 0, 0);
    }
  }

  const int sec = co0 >> 9;
  const int g = (co0 & 511) >> 6;
  const int bg = b * 8 + g;
  if (sec < 2) {
    unsigned short* dst = (sec == 0) ? qt : kt;
#pragma unroll
    for (int ma = 0; ma < 2; ++ma)
#pragma unroll
      for (int nb = 0; nb < 4; ++nb) {
        int n = wn + nb * 16 + l15;
        int p = (h0 + (n >> 5)) * 32 + (n & 31);
        int db = wco + ma * 16 + quad * 4;
        u16x4 pk;
#pragma unroll
        for (int r = 0; r < 4; ++r) pk[r] = bf16rne(acc[ma][nb][r]);
        *(u16x4*)(dst + ((size_t)bg * 1024 + p) * 64 + db) = pk;
      }
    float ps[4];
#pragma unroll
    for (int nb = 0; nb < 4; ++nb) {
      float s = 0.f;
#pragma unroll
      for (int ma = 0; ma < 2; ++ma)
#pragma unroll
        for (int r = 0; r < 4; ++r) s = fmaf(acc[ma][nb][r], acc[ma][nb][r], s);
      s += __shfl_down(s, 32);
      s += __shfl_down(s, 16);
      ps[nb] = s;  // valid in quad==0 lanes
    }
    if (wco == 0 && quad == 0)
#pragma unroll
      for (int nb = 0; nb < 4; ++nb) Snl[wn + nb * 16 + l15] = ps[nb];
    __syncthreads();
    if (wco == 32 && quad == 0) {
      float* ndst = (sec == 0) ? rqn : rkn;
#pragma unroll
      for (int nb = 0; nb < 4; ++nb) {
        int n = wn + nb * 16 + l15;
        int p = (h0 + (n >> 5)) * 32 + (n & 31);
        ndst[bg * 1024 + p] = rsqrtf(Snl[n] + ps[nb] + SMOOTH);
      }
    }
  } else {
#pragma unroll
    for (int ma = 0; ma < 2; ++ma)
#pragma unroll
      for (int nb = 0; nb < 4; ++nb) {
        int n = wn + nb * 16 + l15;
        int p = (h0 + (n >> 5)) * 32 + (n & 31);
#pragma unroll
        for (int r = 0; r < 4; ++r) {
          int d = wco + ma * 16 + quad * 4 + r;
          vt[((size_t)bg * 64 + d) * 1024 + p] = bf16rne(acc[ma][nb][r]);
        }
      }
  }
}

// ---------------------------------------------------------------------------
// Kernel 3: attention, bf16 MFMA. Block = 64 i x (b,g); 4 waves, 16 i each.
// R14: (1) K staged with row permutation perm(j)=(j&3)*16+(j>>2) so MFMA #nb
// lane l15 supplies logical j = 4*l15+nb -> the S-tile's 4 nb-values per
// output row are at consecutive columns -> S writes become 4x u16x4 instead
// of 16x scalar ds_write_b16; rkn loads become one float4.
// (2) K/V staging double-buffered through registers: jt+1's global loads
// issue before the compute barrier, hiding global latency.
// GEMM2 unchanged (Sw holds logical-j layout).
// ---------------------------------------------------------------------------
__global__ __launch_bounds__(256) void attn_mfma(
    const unsigned short* __restrict__ qt, const unsigned short* __restrict__ kt,
    const unsigned short* __restrict__ vt, const float* __restrict__ rqn,
    const float* __restrict__ rkn, unsigned short* __restrict__ aob) {
  __shared__ __align__(16) unsigned short Kl[64 * 72];  // [perm(j)][d]
  __shared__ __align__(16) unsigned short Vl[64 * 72];  // [d][j]
  __shared__ __align__(16) unsigned short Sl[64 * 72];  // [i][j], 16 rows/wave

  const int tid = threadIdx.x;
  const int lane = tid & 63, wave = tid >> 6;
  const int l15 = lane & 15, quad = lane >> 4;
  const int bg = blockIdx.x;  // fastest -> same-bg blocks share XCD L2
  const int i0 = blockIdx.y * 64;
  const int iw = i0 + wave * 16;
  const int b = bg >> 3, g = bg & 7;

  // Staging decode (2 granules per thread)
  const int c8a = tid & 7, rowa = tid >> 3;          // granule 0: rows 0..31
  const int c8b = c8a, rowb = rowa + 32;             // granule 1: rows 32..63
  const int pra = (rowa & 3) * 16 + (rowa >> 2);     // perm for K
  const int prb = (rowb & 3) * 16 + (rowb >> 2);

  bf16x8 qf[2];
#pragma unroll
  for (int ks = 0; ks < 2; ++ks)
    qf[ks] = *(const bf16x8*)(
        qt + ((size_t)bg * 1024 + iw + l15) * 64 + ks * 32 + quad * 8);

  float rq[4];
#pragma unroll
  for (int r = 0; r < 4; ++r) rq[r] = rqn[bg * 1024 + iw + quad * 4 + r];

  f32x4 oacc[4];
  for (int nf = 0; nf < 4; ++nf) oacc[nf] = (f32x4){0.f, 0.f, 0.f, 0.f};

  unsigned short* Sw = Sl + wave * 16 * 72;

  // Register prefetch of jt=0
  u32x4 rk0, rk1, rv0, rv1;
  rk0 = *(const u32x4*)(kt + ((size_t)bg * 1024 + 0 + rowa) * 64 + c8a * 8);
  rk1 = *(const u32x4*)(kt + ((size_t)bg * 1024 + 0 + rowb) * 64 + c8b * 8);
  rv0 = *(const u32x4*)(vt + ((size_t)bg * 64 + rowa) * 1024 + 0 + c8a * 8);
  rv1 = *(const u32x4*)(vt + ((size_t)bg * 64 + rowb) * 1024 + 0 + c8b * 8);

  for (int jt = 0; jt < 16; ++jt) {
    const int j0 = jt * 64;
    __syncthreads();  // prior iter's LDS reads done
    *(u32x4*)(Kl + pra * 72 + c8a * 8) = rk0;
    *(u32x4*)(Kl + prb * 72 + c8b * 8) = rk1;
    *(u32x4*)(Vl + rowa * 72 + c8a * 8) = rv0;
    *(u32x4*)(Vl + rowb * 72 + c8b * 8) = rv1;
    // Issue next tile's global loads before the compute barrier.
    u32x4 nk0, nk1, nv0, nv1;
    if (jt < 15) {
      const int j1 = j0 + 64;
      nk0 = *(const u32x4*)(kt + ((size_t)bg * 1024 + j1 + rowa) * 64 + c8a * 8);
      nk1 = *(const u32x4*)(kt + ((size_t)bg * 1024 + j1 + rowb) * 64 + c8b * 8);
      nv0 = *(const u32x4*)(vt + ((size_t)bg * 64 + rowa) * 1024 + j1 + c8a * 8);
      nv1 = *(const u32x4*)(vt + ((size_t)bg * 64 + rowb) * 1024 + j1 + c8b * 8);
    }
    __syncthreads();

    f32x4 sacc[4];
    for (int nb = 0; nb < 4; ++nb) sacc[nb] = (f32x4){0.f, 0.f, 0.f, 0.f};
#pragma unroll
    for (int ks = 0; ks < 2; ++ks) {
#pragma unroll
      for (int nb = 0; nb < 4; ++nb) {
        // physical row nb*16+l15 = perm(4*l15+nb): logical j = 4*l15+nb
        bf16x8 kf = *(const bf16x8*)(Kl + (nb * 16 + l15) * 72 + ks * 32 + quad * 8);
        sacc[nb] = __builtin_amdgcn_mfma_f32_16x16x32_bf16(
            qf[ks], kf, sacc[nb], 0, 0, 0);
      }
    }

    // Normalize + pack: lane holds S[quad*4+r][4*l15+nb] -> u16x4 per r.
    float4 rk4 = *(const float4*)(rkn + bg * 1024 + j0 + 4 * l15);
#pragma unroll
    for (int r = 0; r < 4; ++r) {
      u16x4 pk;
      pk[0] = bf16rne(sacc[0][r] * (rq[r] * rk4.x));
      pk[1] = bf16rne(sacc[1][r] * (rq[r] * rk4.y));
      pk[2] = bf16rne(sacc[2][r] * (rq[r] * rk4.z));
      pk[3] = bf16rne(sacc[3][r] * (rq[r] * rk4.w));
      *(u16x4*)(Sw + (quad * 4 + r) * 72 + 4 * l15) = pk;
    }
    // Sw is wave-private: lgkmcnt orders write->read, no barrier needed.
#pragma unroll
    for (int ks2 = 0; ks2 < 2; ++ks2) {
      bf16x8 sa = *(const bf16x8*)(Sw + l15 * 72 + ks2 * 32 + quad * 8);
#pragma unroll
      for (int nf = 0; nf < 4; ++nf) {
        bf16x8 vb = *(const bf16x8*)(Vl + (l15 + 16 * nf) * 72 + ks2 * 32 + quad * 8);
        oacc[nf] = __builtin_amdgcn_mfma_f32_16x16x32_bf16(sa, vb, oacc[nf], 0, 0, 0);
      }
    }
    if (jt < 15) {
      rk0 = nk0; rk1 = nk1; rv0 = nv0; rv1 = nv1;
    }
  }

#pragma unroll
  for (int nf = 0; nf < 4; ++nf)
#pragma unroll
    for (int r = 0; r < 4; ++r) {
      int i = iw + quad * 4 + r;
      int d = l15 + 16 * nf;
      aob[((size_t)(b * 1024) + i) * 512 + g * 64 + d] = bf16rne(oacc[nf][r]);
    }
}

// ---------------------------------------------------------------------------
// Kernel 4: 1x1 conv bf16 MFMA (M=512co, N=8192p, K=512ci) + BN stats.
// ---------------------------------------------------------------------------
__global__ __launch_bounds__(256) void conv1x1_mfma(
    const unsigned short* __restrict__ wor, const unsigned short* __restrict__ aob,
    unsigned short* __restrict__ yb, float* __restrict__ sums,
    float* __restrict__ sumsq) {
  __shared__ __align__(16) unsigned short Wl[64 * 40];
  __shared__ __align__(16) unsigned short Bl[64 * 40];

  const int tid = threadIdx.x;
  const int lane = tid & 63, wave = tid >> 6;
  const int l15 = lane & 15, quad = lane >> 4;
  const int wco = (wave & 1) * 32;
  const int wp = (wave >> 1) * 32;
  const int p0 = blockIdx.x * 64;
  const int co0 = blockIdx.y * 64;
  const int b = blockIdx.z;

  f32x4 acc[2][2];
  for (int ma = 0; ma < 2; ++ma)
    for (int nb = 0; nb < 2; ++nb) acc[ma][nb] = (f32x4){0.f, 0.f, 0.f, 0.f};

  for (int ci0 = 0; ci0 < 512; ci0 += 32) {
    __syncthreads();
    {
      int c4 = tid & 3, co = tid >> 2;
      *(u32x4*)(Wl + co * 40 + c4 * 8) =
          *(const u32x4*)(wor + (size_t)(co0 + co) * 512 + ci0 + c4 * 8);
      *(u32x4*)(Bl + co * 40 + c4 * 8) =
          *(const u32x4*)(aob + ((size_t)(b * 1024) + p0 + co) * 512 + ci0 + c4 * 8);
    }
    __syncthreads();

    bf16x8 af[2], bf[2];
#pragma unroll
    for (int ma = 0; ma < 2; ++ma)
      af[ma] = *(const bf16x8*)(Wl + (wco + ma * 16 + l15) * 40 + quad * 8);
#pragma unroll
    for (int nb = 0; nb < 2; ++nb)
      bf[nb] = *(const bf16x8*)(Bl + (wp + nb * 16 + l15) * 40 + quad * 8);
#pragma unroll
    for (int ma = 0; ma < 2; ++ma)
#pragma unroll
      for (int nb = 0; nb < 2; ++nb)
        acc[ma][nb] = __builtin_amdgcn_mfma_f32_16x16x32_bf16(
            af[ma], bf[nb], acc[ma][nb], 0, 0, 0);
  }

#pragma unroll
  for (int ma = 0; ma < 2; ++ma)
#pragma unroll
    for (int r = 0; r < 4; ++r) {
      int co = co0 + wco + ma * 16 + quad * 4 + r;
      float s1 = 0.f, s2 = 0.f;
#pragma unroll
      for (int nb = 0; nb < 2; ++nb) {
        float v = acc[ma][nb][r];
        yb[((size_t)(b * 512) + co) * 1024 + p0 + wp + nb * 16 + l15] = bf16rne(v);
        s1 += v;
        s2 = fmaf(v, v, s2);
      }
      for (int off = 8; off >= 1; off >>= 1) {
        s1 += __shfl_down(s1, off, 16);
        s2 += __shfl_down(s2, off, 16);
      }
      if (l15 == 0) {
        atomicAdd(&sums[co], s1);
        atomicAdd(&sumsq[co], s2);
      }
    }
}

// ---------------------------------------------------------------------------
// Kernel 5: BatchNorm (batch stats, biased var) + ReLU. bf16 in, fp32 out.
// ---------------------------------------------------------------------------
__global__ void bn_kernel(const unsigned short* __restrict__ yb,
                          const float* __restrict__ sums,
                          const float* __restrict__ sumsq,
                          const float* __restrict__ gamma,
                          const float* __restrict__ beta,
                          float* __restrict__ out) {
  int idx = blockIdx.x * 256 + threadIdx.x;
  int c = (idx >> 8) & 511;
  u16x4 vb = *(const u16x4*)(yb + (size_t)idx * 4);
  float mean = sums[c] * (1.f / 8192.f);
  float var = sumsq[c] * (1.f / 8192.f) - mean * mean;
  float sc = gamma[c] * rsqrtf(var + BN_EPS);
  float sh = beta[c] - mean * sc;
  float4 r;
  r.x = fmaxf(0.f, fmaf(b2f(vb[0]), sc, sh));
  r.y = fmaxf(0.f, fmaf(b2f(vb[1]), sc, sh));
  r.z = fmaxf(0.f, fmaf(b2f(vb[2]), sc, sh));
  r.w = fmaxf(0.f, fmaf(b2f(vb[3]), sc, sh));
  ((float4*)out)[idx] = r;
}

// ---------------------------------------------------------------------------
extern "C" void kernel_launch(void* const* d_in, const int* in_sizes, int n_in,
                              void* d_out, int out_size, void* d_ws,
                              size_t ws_size, hipStream_t stream) {
  const float* x = (const float*)d_in[0];
  const float* wq = (const float*)d_in[1];
  const float* wo = (const float*)d_in[2];
  const float* gamma = (const float*)d_in[3];
  const float* beta = (const float*)d_in[4];
  float* out = (float*)d_out;

  unsigned short* qt = (unsigned short*)d_ws;          // [64][1024][64]
  unsigned short* kt = qt + (size_t)4194304;
  unsigned short* vt = kt + (size_t)4194304;           // [64][64][1024]
  unsigned short* aob = vt + (size_t)4194304;          // [8][1024][512]
  unsigned short* wqr2 = aob + (size_t)4194304;        // [16][24][4][9][64][8]
  unsigned short* wor = wqr2 + (size_t)7077888;        // [512][512]
  unsigned short* xrp2 = wor + (size_t)262144;         // [16][4][8][34][34][8]+pad
  float* rqn = (float*)(xrp2 + (size_t)4736000);       // [64][1024]
  float* rkn = rqn + 65536;
  unsigned short* yb = (unsigned short*)(rkn + 65536); // [8][512][1024] bf16
  float* sums = (float*)(yb + (size_t)4194304);
  float* sumsq = sums + 512;

  hipMemsetAsync(xrp2, 0, (size_t)4736000 * 2, stream);
  prep_kernel<<<dim3(4608), 256, 0, stream>>>(wq, wqr2, x, xrp2, wo, wor, sums,
                                              sumsq);
  conv3x3_mfma<<<dim3(8, 24, 8), 256, 0, stream>>>(wqr2, xrp2, qt, kt, vt, rqn,
                                                   rkn);
  attn_mfma<<<dim3(64, 16), 256, 0, stream>>>(qt, kt, vt, rqn, rkn, aob);
  conv1x1_mfma<<<dim3(16, 8, 8), 256, 0, stream>>>(wor, aob, yb, sums, sumsq);
  bn_kernel<<<dim3(4096), 256, 0, stream>>>(yb, sums, sumsq, gamma, beta, out);
}

// Round 15
// 266.400 us; speedup vs baseline: 1.2250x; 1.0942x over previous
//
#include <hip/hip_runtime.h>
#include <math.h>

// x: [8,512,32,32] fp32 | W_qkv: [1536,512,3,3] fp32 | W_out: [512,512,1,1]
// gamma/beta: [512] | out: [8,512,32,32] fp32
// G=8 heads, D=64 head dim, N=1024 seq (h*w), B=8

#define SMOOTH 1e-4f
#define BN_EPS 1e-5f

typedef __attribute__((ext_vector_type(8))) short bf16x8;
typedef __attribute__((ext_vector_type(8))) unsigned short u16x8;
typedef __attribute__((ext_vector_type(4))) float f32x4;
typedef __attribute__((ext_vector_type(4))) unsigned int u32x4;
typedef __attribute__((ext_vector_type(4))) unsigned short u16x4;

__device__ inline unsigned short bf16rne(float f) {
  unsigned int u = __float_as_uint(f);
  u += 0x7fff + ((u >> 16) & 1);
  return (unsigned short)(u >> 16);
}
__device__ inline float b2f(unsigned short u) {
  return __uint_as_float((unsigned int)u << 16);
}

// Async 16B global->LDS DMA (gfx950). LDS dest = wave-uniform base + lane*16.
// RULE (R8): lane gptr MUST be base + lane*16 (contiguous 1KB/wave),
// else ~4-5x HBM overfetch.
typedef __attribute__((address_space(1))) void gvoid;
typedef __attribute__((address_space(3))) void lvoid;
__device__ __forceinline__ void async16(const void* g, void* l) {
  __builtin_amdgcn_global_load_lds((gvoid*)g, (lvoid*)l, 16, 0, 0);
}

// ---------------------------------------------------------------------------
// prep_kernel: merged repacks.
//  [0,768):     W_qkv -> wqr2, COALESCED both sides (R15). Block = one
//               (cotile, ci0c, co-half): loads 32 rows x 288 contiguous
//               floats, LDS-transpose, stores contiguous 16B runs.
//  [768,1280):  x -> xrp2 (padded halo), LDS tile transpose (unchanged).
//  [1280,2304): W_out fp32 -> bf16; first 2 blocks zero BN stats.
// ---------------------------------------------------------------------------
__global__ void prep_kernel(const float* __restrict__ wq,
                            unsigned short* __restrict__ wqr2,
                            const float* __restrict__ x,
                            unsigned short* __restrict__ xrp2,
                            const float* __restrict__ wo,
                            unsigned short* __restrict__ wor,
                            float* __restrict__ sums,
                            float* __restrict__ sumsq) {
  __shared__ float Sh[32 * 292];  // W: 32 rows x 288 (pad 292); X: 64 x 132
  const int tid = threadIdx.x;
  const int bid = blockIdx.x;
  if (bid < 768) {
    // ---- repack W_qkv (coalesced) ----
    const int cotile = bid / 32;
    const int rem = bid - cotile * 32;
    const int ci0c = rem >> 1, cohalf = rem & 1;
    // Load 32 co-rows x 288 floats (contiguous per row): 2304 float4s.
#pragma unroll
    for (int k = 0; k < 9; ++k) {
      int idx = tid + k * 256;
      int row = idx / 72, col = idx - row * 72;
      *(float4*)(Sh + row * 292 + col * 4) =
          *(const float4*)(wq +
                           (size_t)(cotile * 64 + cohalf * 32 + row) * 4608 +
                           ci0c * 288 + col * 4);
    }
    __syncthreads();
    // Store 1152 u16x8 granules, consecutive threads -> consecutive 16B.
    const size_t wbase = (size_t)(ci0c * 24 + cotile) * 18432;
#pragma unroll
    for (int k = 0; k < 5; ++k) {
      int j = tid + k * 256;
      if (j < 1152) {
        int co_l = j & 31;
        int g36 = j >> 5;  // 0..35
        int c4 = g36 / 9, tt = g36 - c4 * 9;
        u16x8 pk;
#pragma unroll
        for (int e = 0; e < 8; ++e)
          pk[e] = bf16rne(Sh[co_l * 292 + (c4 * 8 + e) * 9 + tt]);
        *(u16x8*)(wqr2 + wbase +
                  (size_t)((c4 * 9 + tt) * 64 + cohalf * 32 + co_l) * 8) = pk;
      }
    }
  } else if (bid < 1280) {
    // ---- repack x (LDS tile transpose) ----
    const int bx = bid - 768;
    const int p0 = (bx & 7) * 128;
    const int ci0 = ((bx >> 3) & 7) * 64;
    const int b = bx >> 6;
    for (int k = 0; k < 8; ++k) {
      int idx = tid + k * 256;
      int c4 = idx & 31, row = idx >> 5;
      *(float4*)(Sh + row * 132 + c4 * 4) =
          *(const float4*)(x + ((size_t)(b * 512 + ci0 + row)) * 1024 + p0 + c4 * 4);
    }
    __syncthreads();
    const int pl = tid >> 1, half = tid & 1;
    const int p = p0 + pl;
    const int h = p >> 5, w = p & 31;
#pragma unroll
    for (int v = 0; v < 8; ++v) {
      u16x4 pk;
#pragma unroll
      for (int e = 0; e < 4; ++e)
        pk[e] = bf16rne(Sh[(half * 32 + v * 4 + e) * 132 + pl]);
      int cc = ci0 + half * 32 + v * 4;
      int ci0c = cc >> 5, c4 = (cc >> 3) & 3, e0 = cc & 7;
      size_t gran =
          (size_t)((ci0c * 4 + c4) * 8 + b) * 1156 + (h + 1) * 34 + (w + 1);
      *(u16x4*)(xrp2 + gran * 8 + e0) = pk;
    }
  } else {
    // ---- repack W_out + zero stats ----
    const int rb = bid - 1280;
    int idx = rb * 256 + tid;
    wor[idx] = bf16rne(wo[idx]);
    if (rb < 2) {
      sums[idx] = 0.f;
      sumsq[idx] = 0.f;
    }
  }
}

// ---------------------------------------------------------------------------
// Kernel 1: 3x3 conv bf16 MFMA implicit GEMM — R10/R13 version VERBATIM
// (measured optimum: 107us, MfmaUtil 50%, 0 bank conflicts, LDS-port bound).
// ---------------------------------------------------------------------------
__global__ __launch_bounds__(256) void conv3x3_mfma(
    const unsigned short* __restrict__ wqr2,
    const unsigned short* __restrict__ xrp2,
    unsigned short* __restrict__ qt, unsigned short* __restrict__ kt,
    unsigned short* __restrict__ vt, float* __restrict__ rqn,
    float* __restrict__ rkn) {
  __shared__ __align__(16) unsigned short Wl[2304 * 8];     // 36864 B
  __shared__ __align__(16) unsigned short Xl[4 * 256 * 8];  // 16384 B
  __shared__ float Snl[128];                                // norm partials

  const int tid = threadIdx.x;
  const int lane = tid & 63;
  const int wave = tid >> 6;
  const int wco = (wave & 1) * 32;
  const int wn = (wave >> 1) * 64;
  const int l15 = lane & 15;
  const int quad = lane >> 4;
  const int h0 = blockIdx.x * 4;
  const int co0 = blockIdx.y * 64;
  const int b = blockIdx.z;

  f32x4 acc[2][4];
  for (int ma = 0; ma < 2; ++ma)
    for (int nb = 0; nb < 4; ++nb) acc[ma][nb] = (f32x4){0.f, 0.f, 0.f, 0.f};

  for (int ci0 = 0; ci0 < 512; ci0 += 32) {
    const int ci0c = ci0 >> 5;
    __syncthreads();  // prior iter's readers done
    const unsigned short* wsrc =
        wqr2 + (size_t)(ci0c * 24 + (co0 >> 6)) * 18432;
    {
      int cbase = wave * 9;
#pragma unroll
      for (int j = 0; j < 9; ++j) {
        int c = cbase + j;
        async16(wsrc + (size_t)c * 512 + lane * 8, Wl + (size_t)c * 512);
      }
    }
    const unsigned short* xsrc =
        xrp2 + ((size_t)((ci0c * 4 + wave) * 8 + b) * 1156 + h0 * 34) * 8;
#pragma unroll
    for (int j = 0; j < 4; ++j)
      async16(xsrc + (size_t)j * 512 + lane * 8,
              Xl + (size_t)(wave * 256 + j * 64) * 8);
    __syncthreads();  // drains vmcnt before frag reads

#pragma unroll
    for (int t = 0; t < 9; ++t) {
      const int ky = t / 3, kx = t - ky * 3;
      bf16x8 af[2], bfr[4];
#pragma unroll
      for (int ma = 0; ma < 2; ++ma)
        af[ma] = *(const bf16x8*)(
            Wl + (size_t)((quad * 9 + t) * 64 + wco + ma * 16 + l15) * 8);
#pragma unroll
      for (int nb = 0; nb < 4; ++nb) {
        int n = wn + nb * 16 + l15;
        int hh = (n >> 5) + ky;
        int wi = (n & 31) + kx;
        bfr[nb] = *(const bf16x8*)(Xl + (size_t)(quad * 256 + hh * 34 + wi) * 8);
      }
#pragma unroll
      for (int ma = 0; ma < 2; ++ma)
#pragma unroll
        for (int nb = 0; nb < 4; ++nb)
          acc[ma][nb] = __builtin_amdgcn_mfma_f32_16x16x32_bf16(
              af[ma], bfr[nb], acc[ma][nb], 0, 0, 0);
    }
  }

  const int sec = co0 >> 9;
  const int g = (co0 & 511) >> 6;
  const int bg = b * 8 + g;
  if (sec < 2) {
    unsigned short* dst = (sec == 0) ? qt : kt;
#pragma unroll
    for (int ma = 0; ma < 2; ++ma)
#pragma unroll
      for (int nb = 0; nb < 4; ++nb) {
        int n = wn + nb * 16 + l15;
        int p = (h0 + (n >> 5)) * 32 + (n & 31);
        int db = wco + ma * 16 + quad * 4;
        u16x4 pk;
#pragma unroll
        for (int r = 0; r < 4; ++r) pk[r] = bf16rne(acc[ma][nb][r]);
        *(u16x4*)(dst + ((size_t)bg * 1024 + p) * 64 + db) = pk;
      }
    float ps[4];
#pragma unroll
    for (int nb = 0; nb < 4; ++nb) {
      float s = 0.f;
#pragma unroll
      for (int ma = 0; ma < 2; ++ma)
#pragma unroll
        for (int r = 0; r < 4; ++r) s = fmaf(acc[ma][nb][r], acc[ma][nb][r], s);
      s += __shfl_down(s, 32);
      s += __shfl_down(s, 16);
      ps[nb] = s;  // valid in quad==0 lanes
    }
    if (wco == 0 && quad == 0)
#pragma unroll
      for (int nb = 0; nb < 4; ++nb) Snl[wn + nb * 16 + l15] = ps[nb];
    __syncthreads();
    if (wco == 32 && quad == 0) {
      float* ndst = (sec == 0) ? rqn : rkn;
#pragma unroll
      for (int nb = 0; nb < 4; ++nb) {
        int n = wn + nb * 16 + l15;
        int p = (h0 + (n >> 5)) * 32 + (n & 31);
        ndst[bg * 1024 + p] = rsqrtf(Snl[n] + ps[nb] + SMOOTH);
      }
    }
  } else {
#pragma unroll
    for (int ma = 0; ma < 2; ++ma)
#pragma unroll
      for (int nb = 0; nb < 4; ++nb) {
        int n = wn + nb * 16 + l15;
        int p = (h0 + (n >> 5)) * 32 + (n & 31);
#pragma unroll
        for (int r = 0; r < 4; ++r) {
          int d = wco + ma * 16 + quad * 4 + r;
          vt[((size_t)bg * 64 + d) * 1024 + p] = bf16rne(acc[ma][nb][r]);
        }
      }
  }
}

// ---------------------------------------------------------------------------
// Kernel 3: attention, bf16 MFMA. R15: wave i-tile 32 (was 16) -> 20 b128
// reads per 32 MFMA per jt (0.625 reads/MFMA, -45% LDS traffic). Block =
// 128 thr x 2 waves = 64 i; grid (64,16); LDS 27.6KB unchanged.
// K perm + register double-buffer of K/V staging kept from R14.
// ---------------------------------------------------------------------------
__global__ __launch_bounds__(128) void attn_mfma(
    const unsigned short* __restrict__ qt, const unsigned short* __restrict__ kt,
    const unsigned short* __restrict__ vt, const float* __restrict__ rqn,
    const float* __restrict__ rkn, unsigned short* __restrict__ aob) {
  __shared__ __align__(16) unsigned short Kl[64 * 72];  // [perm(j)][d]
  __shared__ __align__(16) unsigned short Vl[64 * 72];  // [d][j]
  __shared__ __align__(16) unsigned short Sl[64 * 72];  // [i][j], 32 rows/wave

  const int tid = threadIdx.x;
  const int lane = tid & 63, wave = tid >> 6;  // wave 0..1
  const int l15 = lane & 15, quad = lane >> 4;
  const int bg = blockIdx.x;  // fastest -> same-bg blocks share XCD L2
  const int i0 = blockIdx.y * 64;
  const int iw = i0 + wave * 32;
  const int b = bg >> 3, g = bg & 7;

  // Staging decode: 4 K granules + 4 V granules per thread.
  int srow[4], sperm[4], sc8[4];
#pragma unroll
  for (int s = 0; s < 4; ++s) {
    int gidx = tid + s * 128;
    sc8[s] = gidx & 7;
    srow[s] = gidx >> 3;  // 0..63
    sperm[s] = (srow[s] & 3) * 16 + (srow[s] >> 2);
  }

  bf16x8 qf[2][2];
#pragma unroll
  for (int ma = 0; ma < 2; ++ma)
#pragma unroll
    for (int ks = 0; ks < 2; ++ks)
      qf[ma][ks] = *(const bf16x8*)(
          qt + ((size_t)bg * 1024 + iw + ma * 16 + l15) * 64 + ks * 32 + quad * 8);

  float rq[2][4];
#pragma unroll
  for (int ma = 0; ma < 2; ++ma)
#pragma unroll
    for (int r = 0; r < 4; ++r)
      rq[ma][r] = rqn[bg * 1024 + iw + ma * 16 + quad * 4 + r];

  f32x4 oacc[2][4];
  for (int mf = 0; mf < 2; ++mf)
    for (int nf = 0; nf < 4; ++nf) oacc[mf][nf] = (f32x4){0.f, 0.f, 0.f, 0.f};

  unsigned short* Sw = Sl + wave * 32 * 72;

  // Register prefetch of jt=0.
  u32x4 rk[4], rv[4];
#pragma unroll
  for (int s = 0; s < 4; ++s) {
    rk[s] = *(const u32x4*)(kt + ((size_t)bg * 1024 + srow[s]) * 64 + sc8[s] * 8);
    rv[s] = *(const u32x4*)(vt + ((size_t)bg * 64 + srow[s]) * 1024 + sc8[s] * 8);
  }

  for (int jt = 0; jt < 16; ++jt) {
    const int j0 = jt * 64;
    __syncthreads();  // prior iter's LDS reads done
#pragma unroll
    for (int s = 0; s < 4; ++s) {
      *(u32x4*)(Kl + sperm[s] * 72 + sc8[s] * 8) = rk[s];
      *(u32x4*)(Vl + srow[s] * 72 + sc8[s] * 8) = rv[s];
    }
    u32x4 nk[4], nv[4];
    if (jt < 15) {
      const int j1 = j0 + 64;
#pragma unroll
      for (int s = 0; s < 4; ++s) {
        nk[s] = *(const u32x4*)(kt + ((size_t)bg * 1024 + j1 + srow[s]) * 64 + sc8[s] * 8);
        nv[s] = *(const u32x4*)(vt + ((size_t)bg * 64 + srow[s]) * 1024 + j1 + sc8[s] * 8);
      }
    }
    __syncthreads();

    f32x4 sacc[2][4];
    for (int ma = 0; ma < 2; ++ma)
      for (int nb = 0; nb < 4; ++nb) sacc[ma][nb] = (f32x4){0.f, 0.f, 0.f, 0.f};
#pragma unroll
    for (int ks = 0; ks < 2; ++ks) {
#pragma unroll
      for (int nb = 0; nb < 4; ++nb) {
        // physical row nb*16+l15 = perm(4*l15+nb): logical j = 4*l15+nb
        bf16x8 kf = *(const bf16x8*)(Kl + (nb * 16 + l15) * 72 + ks * 32 + quad * 8);
#pragma unroll
        for (int ma = 0; ma < 2; ++ma)
          sacc[ma][nb] = __builtin_amdgcn_mfma_f32_16x16x32_bf16(
              qf[ma][ks], kf, sacc[ma][nb], 0, 0, 0);
      }
    }

    // Normalize + pack: lane holds S[ma*16+quad*4+r][4*l15+nb].
    float4 rk4 = *(const float4*)(rkn + bg * 1024 + j0 + 4 * l15);
#pragma unroll
    for (int ma = 0; ma < 2; ++ma)
#pragma unroll
      for (int r = 0; r < 4; ++r) {
        u16x4 pk;
        pk[0] = bf16rne(sacc[ma][0][r] * (rq[ma][r] * rk4.x));
        pk[1] = bf16rne(sacc[ma][1][r] * (rq[ma][r] * rk4.y));
        pk[2] = bf16rne(sacc[ma][2][r] * (rq[ma][r] * rk4.z));
        pk[3] = bf16rne(sacc[ma][3][r] * (rq[ma][r] * rk4.w));
        *(u16x4*)(Sw + (ma * 16 + quad * 4 + r) * 72 + 4 * l15) = pk;
      }
    // Sw is wave-private: lgkmcnt orders write->read, no barrier needed.
#pragma unroll
    for (int ks2 = 0; ks2 < 2; ++ks2) {
      bf16x8 sa[2];
#pragma unroll
      for (int mf = 0; mf < 2; ++mf)
        sa[mf] = *(const bf16x8*)(Sw + (mf * 16 + l15) * 72 + ks2 * 32 + quad * 8);
#pragma unroll
      for (int nf = 0; nf < 4; ++nf) {
        bf16x8 vb = *(const bf16x8*)(Vl + (l15 + 16 * nf) * 72 + ks2 * 32 + quad * 8);
#pragma unroll
        for (int mf = 0; mf < 2; ++mf)
          oacc[mf][nf] = __builtin_amdgcn_mfma_f32_16x16x32_bf16(
              sa[mf], vb, oacc[mf][nf], 0, 0, 0);
      }
    }
    if (jt < 15) {
#pragma unroll
      for (int s = 0; s < 4; ++s) {
        rk[s] = nk[s];
        rv[s] = nv[s];
      }
    }
  }

#pragma unroll
  for (int mf = 0; mf < 2; ++mf)
#pragma unroll
    for (int nf = 0; nf < 4; ++nf)
#pragma unroll
      for (int r = 0; r < 4; ++r) {
        int i = iw + mf * 16 + quad * 4 + r;
        int d = l15 + 16 * nf;
        aob[((size_t)(b * 1024) + i) * 512 + g * 64 + d] = bf16rne(oacc[mf][nf][r]);
      }
}

// ---------------------------------------------------------------------------
// Kernel 4: 1x1 conv bf16 MFMA (M=512co, N=8192p, K=512ci) + BN stats.
// ---------------------------------------------------------------------------
__global__ __launch_bounds__(256) void conv1x1_mfma(
    const unsigned short* __restrict__ wor, const unsigned short* __restrict__ aob,
    unsigned short* __restrict__ yb, float* __restrict__ sums,
    float* __restrict__ sumsq) {
  __shared__ __align__(16) unsigned short Wl[64 * 40];
  __shared__ __align__(16) unsigned short Bl[64 * 40];

  const int tid = threadIdx.x;
  const int lane = tid & 63, wave = tid >> 6;
  const int l15 = lane & 15, quad = lane >> 4;
  const int wco = (wave & 1) * 32;
  const int wp = (wave >> 1) * 32;
  const int p0 = blockIdx.x * 64;
  const int co0 = blockIdx.y * 64;
  const int b = blockIdx.z;

  f32x4 acc[2][2];
  for (int ma = 0; ma < 2; ++ma)
    for (int nb = 0; nb < 2; ++nb) acc[ma][nb] = (f32x4){0.f, 0.f, 0.f, 0.f};

  for (int ci0 = 0; ci0 < 512; ci0 += 32) {
    __syncthreads();
    {
      int c4 = tid & 3, co = tid >> 2;
      *(u32x4*)(Wl + co * 40 + c4 * 8) =
          *(const u32x4*)(wor + (size_t)(co0 + co) * 512 + ci0 + c4 * 8);
      *(u32x4*)(Bl + co * 40 + c4 * 8) =
          *(const u32x4*)(aob + ((size_t)(b * 1024) + p0 + co) * 512 + ci0 + c4 * 8);
    }
    __syncthreads();

    bf16x8 af[2], bf[2];
#pragma unroll
    for (int ma = 0; ma < 2; ++ma)
      af[ma] = *(const bf16x8*)(Wl + (wco + ma * 16 + l15) * 40 + quad * 8);
#pragma unroll
    for (int nb = 0; nb < 2; ++nb)
      bf[nb] = *(const bf16x8*)(Bl + (wp + nb * 16 + l15) * 40 + quad * 8);
#pragma unroll
    for (int ma = 0; ma < 2; ++ma)
#pragma unroll
      for (int nb = 0; nb < 2; ++nb)
        acc[ma][nb] = __builtin_amdgcn_mfma_f32_16x16x32_bf16(
            af[ma], bf[nb], acc[ma][nb], 0, 0, 0);
  }

#pragma unroll
  for (int ma = 0; ma < 2; ++ma)
#pragma unroll
    for (int r = 0; r < 4; ++r) {
      int co = co0 + wco + ma * 16 + quad * 4 + r;
      float s1 = 0.f, s2 = 0.f;
#pragma unroll
      for (int nb = 0; nb < 2; ++nb) {
        float v = acc[ma][nb][r];
        yb[((size_t)(b * 512) + co) * 1024 + p0 + wp + nb * 16 + l15] = bf16rne(v);
        s1 += v;
        s2 = fmaf(v, v, s2);
      }
      for (int off = 8; off >= 1; off >>= 1) {
        s1 += __shfl_down(s1, off, 16);
        s2 += __shfl_down(s2, off, 16);
      }
      if (l15 == 0) {
        atomicAdd(&sums[co], s1);
        atomicAdd(&sumsq[co], s2);
      }
    }
}

// ---------------------------------------------------------------------------
// Kernel 5: BatchNorm (batch stats, biased var) + ReLU. bf16 in, fp32 out.
// ---------------------------------------------------------------------------
__global__ void bn_kernel(const unsigned short* __restrict__ yb,
                          const float* __restrict__ sums,
                          const float* __restrict__ sumsq,
                          const float* __restrict__ gamma,
                          const float* __restrict__ beta,
                          float* __restrict__ out) {
  int idx = blockIdx.x * 256 + threadIdx.x;
  int c = (idx >> 8) & 511;
  u16x4 vb = *(const u16x4*)(yb + (size_t)idx * 4);
  float mean = sums[c] * (1.f / 8192.f);
  float var = sumsq[c] * (1.f / 8192.f) - mean * mean;
  float sc = gamma[c] * rsqrtf(var + BN_EPS);
  float sh = beta[c] - mean * sc;
  float4 r;
  r.x = fmaxf(0.f, fmaf(b2f(vb[0]), sc, sh));
  r.y = fmaxf(0.f, fmaf(b2f(vb[1]), sc, sh));
  r.z = fmaxf(0.f, fmaf(b2f(vb[2]), sc, sh));
  r.w = fmaxf(0.f, fmaf(b2f(vb[3]), sc, sh));
  ((float4*)out)[idx] = r;
}

// ---------------------------------------------------------------------------
extern "C" void kernel_launch(void* const* d_in, const int* in_sizes, int n_in,
                              void* d_out, int out_size, void* d_ws,
                              size_t ws_size, hipStream_t stream) {
  const float* x = (const float*)d_in[0];
  const float* wq = (const float*)d_in[1];
  const float* wo = (const float*)d_in[2];
  const float* gamma = (const float*)d_in[3];
  const float* beta = (const float*)d_in[4];
  float* out = (float*)d_out;

  unsigned short* qt = (unsigned short*)d_ws;          // [64][1024][64]
  unsigned short* kt = qt + (size_t)4194304;
  unsigned short* vt = kt + (size_t)4194304;           // [64][64][1024]
  unsigned short* aob = vt + (size_t)4194304;          // [8][1024][512]
  unsigned short* wqr2 = aob + (size_t)4194304;        // [16][24][4][9][64][8]
  unsigned short* wor = wqr2 + (size_t)7077888;        // [512][512]
  unsigned short* xrp2 = wor + (size_t)262144;         // [16][4][8][34][34][8]+pad
  float* rqn = (float*)(xrp2 + (size_t)4736000);       // [64][1024]
  float* rkn = rqn + 65536;
  unsigned short* yb = (unsigned short*)(rkn + 65536); // [8][512][1024] bf16
  float* sums = (float*)(yb + (size_t)4194304);
  float* sumsq = sums + 512;

  hipMemsetAsync(xrp2, 0, (size_t)4736000 * 2, stream);
  prep_kernel<<<dim3(2304), 256, 0, stream>>>(wq, wqr2, x, xrp2, wo, wor, sums,
                                              sumsq);
  conv3x3_mfma<<<dim3(8, 24, 8), 256, 0, stream>>>(wqr2, xrp2, qt, kt, vt, rqn,
                                                   rkn);
  attn_mfma<<<dim3(64, 16), 128, 0, stream>>>(qt, kt, vt, rqn, rkn, aob);
  conv1x1_mfma<<<dim3(16, 8, 8), 256, 0, stream>>>(wor, aob, yb, sums, sumsq);
  bn_kernel<<<dim3(4096), 256, 0, stream>>>(yb, sums, sumsq, gamma, beta, out);
}